// Round 9
// baseline (293.900 us; speedup 1.0000x reference)
//
#include <hip/hip_runtime.h>
#include <hip/hip_bf16.h>

// ===================== Round 9: barrier-free direct-global MFMA =====================
// Locked: X fp32 [8192][3084]; out fp32 [8192][600]; W math + H1 epilogue +
// bf16-cvt verified (R4). R8 post-mortem: __syncthreads vmcnt(0) drain exposes
// full load latency every K-step regardless of prefetch (m97-class stall);
// all pipes <=15%. Fix: NO LDS, NO barriers — waves load MFMA fragments
// directly from global; compiler pipelines with fine vmcnt. W generated in
// k-panel layout W2[k>>3][n][k&7] so B-frag loads are 256B-contiguous per quad.

#define NFFT   512
#define HOP    128
#define KDIM   3084      // 257*6*2
#define KP     3104      // K padded to 97*32 (panels: 388 = 97*4)
#define NPAN   (KP / 8)  // 388
#define NOUT   600
#define NP     640       // W n padded (5*128)
#define BM     64
#define BN     128

typedef short s16x8 __attribute__((ext_vector_type(8)));
typedef float f32x4 __attribute__((ext_vector_type(4)));

static __device__ __forceinline__ unsigned short bf16_bits(float f) {
    __hip_bfloat16 b = __float2bfloat16(f);   // RNE - R4-verified path
    return *(unsigned short*)&b;
}

static __device__ __forceinline__ s16x8 cvt8(float4 v0, float4 v1) {
    s16x8 r;
    r[0] = (short)bf16_bits(v0.x); r[1] = (short)bf16_bits(v0.y);
    r[2] = (short)bf16_bits(v0.z); r[3] = (short)bf16_bits(v0.w);
    r[4] = (short)bf16_bits(v1.x); r[5] = (short)bf16_bits(v1.y);
    r[6] = (short)bf16_bits(v1.z); r[7] = (short)bf16_bits(v1.w);
    return r;
}

// ---------------- W generation: cos-table per row, k-panel scatter write ----
// W2 element (n,k) lives at ((k>>3)*NP + n)*8 + (k&7).
__global__ __launch_bounds__(256) void gen_W(unsigned short* __restrict__ W2) {
    __shared__ float costab[512];
    __shared__ __align__(16) unsigned short rowbuf[KP];   // 6208 B
    const int l   = blockIdx.x;     // 0..639 (n index)
    const int tid = threadIdx.x;
    const float w0 = 6.283185307179586f / 512.0f;

    *(int4*)(rowbuf + tid * 8) = make_int4(0, 0, 0, 0);
    if (tid < NPAN - 256) *(int4*)(rowbuf + (256 + tid) * 8) = make_int4(0, 0, 0, 0);
    costab[tid]       = __cosf((float)tid * w0);
    costab[tid + 256] = __cosf((float)(tid + 256) * w0);
    __syncthreads();

    if (l < NOUT) {
        const int p = l + 256;
        float env = 0.0f;
#pragma unroll
        for (int tt = 0; tt < 6; ++tt) {
            int m = p - HOP * tt;
            if (m >= 0 && m < NFFT) {
                float w = 0.5f - 0.5f * costab[m];
                env += w * w;
            }
        }
        const float inv = 1.0f / (512.0f * env);
        for (int f = tid; f <= 256; f += 256) {
            float cf = (f == 0 || f == 256) ? 1.0f : 2.0f;
#pragma unroll
            for (int t = 0; t < 6; ++t) {
                int n = p - HOP * t;
                if (n >= 0 && n < NFFT) {
                    float w = 0.5f - 0.5f * costab[n];
                    float scale = cf * w * inv;
                    int a = (f * n) & 511;
                    float c = costab[a];
                    float s = costab[(a + 384) & 511];
                    rowbuf[f * 12 + t * 2 + 0] = bf16_bits(scale * c);
                    rowbuf[f * 12 + t * 2 + 1] = bf16_bits(-scale * s);
                }
            }
        }
    }
    __syncthreads();

    // k-panel scatter: chunk c (8 shorts) -> W2[(c*NP + l)*8]
    for (int c = tid; c < NPAN; c += 256)
        *(int4*)(W2 + ((size_t)c * NP + l) * 8) = *(const int4*)(rowbuf + c * 8);
}

// ---------------- GEMM: out += X * W^T, no LDS, no barriers ------------------
// 256 thr = 4 waves, wave tile 32(m) x 64(n): wm=(w&1)*32, wn=(w>>1)*64.
// Grid 1280 = 128 mt x 5 nt x 2 kidx; split-K at step 48 (steps of 32 k).
__global__ __launch_bounds__(256, 4) void gemm_kernel(
        const float* __restrict__ X,           // fp32 [8192][3084]
        const unsigned short* __restrict__ W2, // bf16 bits, k-panel layout
        float* __restrict__ out) {             // fp32 [8192][600], pre-zeroed
    const int tid = threadIdx.x;
    const int bid  = blockIdx.x;           // 0..1279
    const int xcd  = bid & 7;
    const int rest = bid >> 3;             // 0..159
    const int mt   = xcd * 16 + rest / 10; // 0..127
    const int sub  = rest % 10;
    const int nt   = sub >> 1;             // 0..4
    const int kidx = sub & 1;              // 0/1
    const int mBase = mt * BM;
    const int nBase = nt * BN;

    const int lane = tid & 63;
    const int wave = tid >> 6;
    const int wm   = (wave & 1) * 32;
    const int wn   = (wave >> 1) * 64;
    const int lrow = lane & 15;
    const int quad = lane >> 4;

    const int sBeg = kidx ? 48 : 0;
    const int sEnd = kidx ? 96 : 48;       // step 96 handled in guarded tail (kidx=1)

    // A: rows mBase+wm+i*16+lrow, cols step*32 + quad*8 (+4)
    const float* aP0 = X + (size_t)(mBase + wm + lrow) * KDIM + quad * 8;
    const float* aP1 = aP0 + (size_t)16 * KDIM;
    // B: panel step*4+quad, n = nBase+wn+j*16+lrow
    const unsigned short* bP =
        W2 + ((size_t)(sBeg * 4 + quad) * NP + (nBase + wn + lrow)) * 8;

    f32x4 acc[2][4];
#pragma unroll
    for (int i = 0; i < 2; ++i)
#pragma unroll
        for (int j = 0; j < 4; ++j) acc[i][j] = (f32x4){0.f, 0.f, 0.f, 0.f};

#pragma unroll 2
    for (int step = sBeg; step < sEnd; ++step) {
        s16x8 bfr[4];
#pragma unroll
        for (int j = 0; j < 4; ++j)
            bfr[j] = *(const s16x8*)(const void*)(bP + j * 128);
#pragma unroll
        for (int i = 0; i < 2; ++i) {
            const float* ap = (i ? aP1 : aP0) + step * 32;
            float4 v0 = *(const float4*)(ap);
            float4 v1 = *(const float4*)(ap + 4);
            s16x8 afr = cvt8(v0, v1);
#pragma unroll
            for (int j = 0; j < 4; ++j)
                acc[i][j] = __builtin_amdgcn_mfma_f32_16x16x32_bf16(
                    afr, bfr[j], acc[i][j], 0, 0, 0);
        }
        bP += (size_t)4 * NP * 8;
    }

    if (kidx) {   // tail step 96: k = 3072 + quad*8 (+4); guard vs KDIM=3084
        s16x8 bfr[4];
#pragma unroll
        for (int j = 0; j < 4; ++j)
            bfr[j] = *(const s16x8*)(const void*)(bP + j * 128);  // panels 384..387, zero-padded
        const float4 z4 = make_float4(0.f, 0.f, 0.f, 0.f);
#pragma unroll
        for (int i = 0; i < 2; ++i) {
            const float* ap = (i ? aP1 : aP0) + 96 * 32;
            float4 v0 = (quad < 2) ? *(const float4*)(ap)     : z4;  // cols 3072+q*8..+3
            float4 v1 = (quad < 1) ? *(const float4*)(ap + 4) : z4;  // cols 3076..3079
            s16x8 afr = cvt8(v0, v1);
#pragma unroll
            for (int j = 0; j < 4; ++j)
                acc[i][j] = __builtin_amdgcn_mfma_f32_16x16x32_bf16(
                    afr, bfr[j], acc[i][j], 0, 0, 0);
        }
    }

    // epilogue: H1 layout (n=lane&15, m=quad*4+reg), atomic accumulate
#pragma unroll
    for (int i = 0; i < 2; ++i) {
#pragma unroll
        for (int j = 0; j < 4; ++j) {
            int gn = nBase + wn + j * 16 + lrow;
            if (gn < NOUT) {
#pragma unroll
                for (int r = 0; r < 4; ++r) {
                    int gm = mBase + wm + i * 16 + quad * 4 + r;
                    atomicAdd(out + (size_t)gm * NOUT + gn, acc[i][j][r]);
                }
            }
        }
    }
}

extern "C" void kernel_launch(void* const* d_in, const int* in_sizes, int n_in,
                              void* d_out, int out_size, void* d_ws, size_t ws_size,
                              hipStream_t stream) {
    const float* X = (const float*)d_in[0];
    unsigned short* W2 = (unsigned short*)d_ws;  // 388*640*8*2 B = 3.97 MB
    float* out = (float*)d_out;

    hipMemsetAsync(d_out, 0, (size_t)out_size * sizeof(float), stream);
    gen_W<<<dim3(NP), 256, 0, stream>>>(W2);
    gemm_kernel<<<dim3(128 * 5 * 2), 256, 0, stream>>>(X, W2, out);
}